// Round 2
// baseline (1599.056 us; speedup 1.0000x reference)
//
#include <hip/hip_runtime.h>
#include <math.h>

#define NN    50000
#define NEDGE 250000
#define NHOPE 125000
#define ETOT  375000   // NEDGE + NHOPE
#define NRELS 500
#define BATCH 65536

__device__ __forceinline__ void atomAdd(float* p, float v) { unsafeAtomicAdd(p, v); }

// ---------------- row-wise L2 normalize (one wave per row) ----------------
__global__ __launch_bounds__(256) void l2norm_rows(const float* __restrict__ in,
                                                   float* __restrict__ out, int M, int D) {
  int row  = blockIdx.x * 4 + (threadIdx.x >> 6);
  int lane = threadIdx.x & 63;
  if (row >= M) return;
  const float* r = in + (size_t)row * D;
  float ss = 0.f;
  for (int c = lane; c < D; c += 64) { float v = r[c]; ss += v * v; }
  #pragma unroll
  for (int off = 1; off < 64; off <<= 1) ss += __shfl_xor(ss, off);
  float inv = 1.f / fmaxf(sqrtf(ss), 1e-12f);
  float* o = out + (size_t)row * D;
  for (int c = lane; c < D; c += 64) o[c] = r[c] * inv;
}

// ---------------- generic f32 GEMM: C[i, col0+j] = sum_k A[i,k] * W[j*wsj + k*wsk]
// 64x64 tile, BK=16, 256 threads, 4x4 microtile.
__global__ __launch_bounds__(256) void gemm_f32(const float* __restrict__ A, int M, int Kd, int lda,
                                                const float* __restrict__ W, int wsj, int wsk,
                                                float* __restrict__ C, int ldc, int Ncols, int col0) {
  __shared__ float As[16][68];
  __shared__ float Bs[16][68];
  int tid = threadIdx.x;
  int tx = tid & 15, ty = tid >> 4;
  int row0 = blockIdx.y * 64;
  int colb = blockIdx.x * 64;
  float acc[4][4] = {{0.f}};
  for (int kt = 0; kt < Kd; kt += 16) {
    #pragma unroll
    for (int l = 0; l < 4; ++l) {
      int idx = tid + l * 256;
      int m = idx >> 4;
      int k = idx & 15;
      int gk = kt + k;
      int gm = row0 + m;
      As[k][m] = (gm < M && gk < Kd) ? A[gm * lda + gk] : 0.f;
      int gj = colb + m;
      Bs[k][m] = (gj < Ncols && gk < Kd) ? W[gj * wsj + gk * wsk] : 0.f;
    }
    __syncthreads();
    #pragma unroll
    for (int k = 0; k < 16; ++k) {
      float4 av = *(const float4*)&As[k][ty * 4];
      float4 bv = *(const float4*)&Bs[k][tx * 4];
      float a0[4] = {av.x, av.y, av.z, av.w};
      float b0[4] = {bv.x, bv.y, bv.z, bv.w};
      #pragma unroll
      for (int i = 0; i < 4; ++i)
        #pragma unroll
        for (int j = 0; j < 4; ++j)
          acc[i][j] += a0[i] * b0[j];
    }
    __syncthreads();
  }
  #pragma unroll
  for (int i = 0; i < 4; ++i) {
    int gm = row0 + ty * 4 + i;
    if (gm >= M) continue;
    #pragma unroll
    for (int j = 0; j < 4; ++j) {
      int gj = colb + tx * 4 + j;
      if (gj < Ncols) C[gm * ldc + col0 + gj] = acc[i][j];
    }
  }
}

// ---------------- per-row dot with a2 (two heads, 100 each) ----------------
__global__ __launch_bounds__(256) void dot2h(const float* __restrict__ P, const float* __restrict__ a2,
                                             float* __restrict__ outp, int M) {
  int row  = blockIdx.x * 4 + (threadIdx.x >> 6);
  int lane = threadIdx.x & 63;
  if (row >= M) return;
  const float* pr = P + (size_t)row * 200;
  float s0 = 0.f, s1 = 0.f;
  for (int k = lane; k < 100; k += 64) {
    s0 += pr[k] * a2[k];
    s1 += pr[100 + k] * a2[100 + k];
  }
  #pragma unroll
  for (int off = 1; off < 64; off <<= 1) { s0 += __shfl_xor(s0, off); s1 += __shfl_xor(s1, off); }
  if (lane == 0) { outp[row * 2] = s0; outp[row * 2 + 1] = s1; }
}

// ---------------- per-row dot with a2 (single, 200) ----------------
__global__ __launch_bounds__(256) void dot1(const float* __restrict__ P, const float* __restrict__ a2,
                                            float* __restrict__ outp, int M) {
  int row  = blockIdx.x * 4 + (threadIdx.x >> 6);
  int lane = threadIdx.x & 63;
  if (row >= M) return;
  const float* pr = P + (size_t)row * 200;
  float s = 0.f;
  for (int k = lane; k < 200; k += 64) s += pr[k] * a2[k];
  #pragma unroll
  for (int off = 1; off < 64; off <<= 1) s += __shfl_xor(s, off);
  if (lane == 0) outp[row] = s;
}

// ---------------- layer-1 edge pass (2 heads, 100 cols each) ----------------
__global__ __launch_bounds__(256) void edge1(const int* __restrict__ el, const int* __restrict__ et,
                                             const int* __restrict__ tin,
                                             const float* __restrict__ dstp, const float* __restrict__ relp,
                                             const float* __restrict__ ssrc, const float* __restrict__ sdst,
                                             const float* __restrict__ srel,
                                             float* __restrict__ rowsum, float* __restrict__ acc) {
  int w    = (blockIdx.x * blockDim.x + threadIdx.x) >> 6;
  int lane = threadIdx.x & 63;
  if (w >= ETOT) return;
  int e0, e1;
  const float* r1;
  const float* r2 = nullptr;
  float sr0, sr1;
  if (w < NEDGE) {
    e0 = el[w]; e1 = el[NEDGE + w];
    int t = et[w];
    r1 = relp + t * 200;
    sr0 = srel[t * 2]; sr1 = srel[t * 2 + 1];
  } else {
    int idx = w - NEDGE;
    const int* q = tin + idx * 4;
    e0 = q[3]; e1 = q[0];
    int t1 = q[1], t2 = q[2];
    r1 = relp + t1 * 200; r2 = relp + t2 * 200;
    sr0 = srel[t1 * 2] + srel[t2 * 2];
    sr1 = srel[t1 * 2 + 1] + srel[t2 * 2 + 1];
  }
  float p0 = ssrc[e0 * 2]     + sdst[e1 * 2]     + sr0;
  float p1 = ssrc[e0 * 2 + 1] + sdst[e1 * 2 + 1] + sr1;
  p0 = (p0 > 0.f) ? p0 : 0.2f * p0;
  p1 = (p1 > 0.f) ? p1 : 0.2f * p1;
  float ee0 = expf(-p0), ee1 = expf(-p1);
  if (lane == 0) { atomAdd(rowsum + e0 * 2, ee0); atomAdd(rowsum + e0 * 2 + 1, ee1); }
  const float* d = dstp + (size_t)e1 * 200;
  float* a = acc + (size_t)e0 * 200;
  for (int c = lane; c < 200; c += 64) {
    float rv = r1[c];
    if (r2) rv += r2[c];
    float ee = (c < 100) ? ee0 : ee1;
    atomAdd(a + c, ee * (d[c] + rv));
  }
}

// ---------------- layer-2 edge pass (single head, 200 cols) ----------------
__global__ __launch_bounds__(256) void edge2(const int* __restrict__ el, const int* __restrict__ et,
                                             const int* __restrict__ tin,
                                             const float* __restrict__ dstp, const float* __restrict__ relp,
                                             const float* __restrict__ ssrc, const float* __restrict__ sdst,
                                             const float* __restrict__ srel,
                                             float* __restrict__ rowsum, float* __restrict__ acc) {
  int w    = (blockIdx.x * blockDim.x + threadIdx.x) >> 6;
  int lane = threadIdx.x & 63;
  if (w >= ETOT) return;
  int e0, e1;
  const float* r1;
  const float* r2 = nullptr;
  float sr;
  if (w < NEDGE) {
    e0 = el[w]; e1 = el[NEDGE + w];
    int t = et[w];
    r1 = relp + t * 200;
    sr = srel[t];
  } else {
    int idx = w - NEDGE;
    const int* q = tin + idx * 4;
    e0 = q[3]; e1 = q[0];
    int t1 = q[1], t2 = q[2];
    r1 = relp + t1 * 200; r2 = relp + t2 * 200;
    sr = srel[t1] + srel[t2];
  }
  float p = ssrc[e0] + sdst[e1] + sr;
  p = (p > 0.f) ? p : 0.2f * p;
  float ee = expf(-p);
  if (lane == 0) atomAdd(rowsum + e0, ee);
  const float* d = dstp + (size_t)e1 * 200;
  float* a = acc + (size_t)e0 * 200;
  for (int c = lane; c < 200; c += 64) {
    float rv = r1[c];
    if (r2) rv += r2[c];
    atomAdd(a + c, ee * (d[c] + rv));
  }
}

// ---------------- layer-1 combine: x = elu(srcp + acc/rowsum), in place on acc ----------------
__global__ __launch_bounds__(256) void combine1(const float* __restrict__ srcp,
                                                const float* __restrict__ rowsum,
                                                float* __restrict__ x) {
  int idx = blockIdx.x * 256 + threadIdx.x;
  if (idx >= NN * 200) return;
  int i = idx / 200;
  int c = idx - i * 200;
  int h = (c >= 100) ? 1 : 0;
  float rs = rowsum[i * 2 + h];
  float v = (rs == 0.f) ? 0.f : (srcp[idx] + x[idx] / rs);
  x[idx] = (v > 0.f) ? v : expm1f(v);
}

// ---------------- mask scatter ----------------
__global__ __launch_bounds__(256) void maskset(const int* __restrict__ bi, float* __restrict__ maskA) {
  int t = blockIdx.x * 256 + threadIdx.x;
  if (t < BATCH) maskA[bi[t * 3 + 2]] = 1.0f;
}

// ---------------- final: out = l2norm(x0n @ W_ent + mask * elu(h2)), one wave/row ----------------
__global__ __launch_bounds__(256) void finalk(const float* __restrict__ x0n, const float* __restrict__ W_ent,
                                              const float* __restrict__ srcp2, const float* __restrict__ rowsum2,
                                              const float* __restrict__ maskA, float* __restrict__ out) {
  int row  = blockIdx.x * 4 + (threadIdx.x >> 6);
  int lane = threadIdx.x & 63;
  int wv   = threadIdx.x >> 6;
  __shared__ float xs[4][100];
  if (row >= NN) return;
  const float* xr = x0n + (size_t)row * 100;
  for (int k = lane; k < 100; k += 64) xs[wv][k] = xr[k];
  float rs = rowsum2[row];
  float m = maskA[row];
  float invrs = (rs != 0.f) ? (1.f / rs) : 0.f;
  float pre[4];
  float ss = 0.f;
  #pragma unroll
  for (int l = 0; l < 4; ++l) {
    int c = lane + l * 64;
    float v = 0.f;
    if (c < 200) {
      float dotv = 0.f;
      for (int k = 0; k < 100; ++k) dotv += xs[wv][k] * W_ent[k * 200 + c];
      float h2 = 0.f;
      if (rs != 0.f) h2 = srcp2[(size_t)row * 200 + c] + out[(size_t)row * 200 + c] * invrs;
      float e = (h2 > 0.f) ? h2 : expm1f(h2);
      v = dotv + m * e;
    }
    pre[l] = v;
    ss += v * v;
  }
  #pragma unroll
  for (int off = 1; off < 64; off <<= 1) ss += __shfl_xor(ss, off);
  float inv = 1.f / fmaxf(sqrtf(ss), 1e-12f);
  #pragma unroll
  for (int l = 0; l < 4; ++l) {
    int c = lane + l * 64;
    if (c < 200) out[(size_t)row * 200 + c] = pre[l] * inv;
  }
}

extern "C" void kernel_launch(void* const* d_in, const int* in_sizes, int n_in,
                              void* d_out, int out_size, void* d_ws, size_t ws_size,
                              hipStream_t stream) {
  (void)in_sizes; (void)n_in; (void)out_size; (void)ws_size;
  const float* ent      = (const float*)d_in[0];
  const float* rel      = (const float*)d_in[1];
  const float* a_heads  = (const float*)d_in[3];
  const float* a2_heads = (const float*)d_in[4];
  const float* W_gat    = (const float*)d_in[5];
  const float* a_out    = (const float*)d_in[6];
  const float* a2_out   = (const float*)d_in[7];
  const float* W_ent    = (const float*)d_in[8];
  const int* edge_list  = (const int*)d_in[9];
  const int* edge_type  = (const int*)d_in[10];
  const int* tin        = (const int*)d_in[11];
  const int* binp       = (const int*)d_in[12];

  float* out    = (float*)d_out;
  float* outrel = out + 10000000;   // (500,200)

  float* ws      = (float*)d_ws;
  float* x0n     = ws;               // N*100
  float* bufS    = ws + 5000000;     // N*200 : srcp1 -> srcp2
  float* bufD    = ws + 15000000;    // N*200 : dstp1 -> dstp2
  float* bufX    = ws + 25000000;    // N*200 : acc1 -> x
  float* relp1   = ws + 35000000;    // 500*200
  float* relp2   = ws + 35100000;    // 500*200
  float* ssrc1   = ws + 35200000;    // N*2
  float* sdst1   = ws + 35300000;    // N*2
  float* rowsum1 = ws + 35400000;    // N*2
  float* s2src   = ws + 35500000;    // N
  float* s2dst   = ws + 35550000;    // N
  float* rowsum2 = ws + 35600000;    // N
  float* s2rel   = ws + 35650000;    // 500
  float* srel1   = ws + 35652000;    // 500*2
  float* maskA   = ws + 35654000;    // N

  // zero accumulators (acc2 lives in d_out[0:10M])
  hipMemsetAsync(bufX,    0, (size_t)10000000 * 4, stream);
  hipMemsetAsync(rowsum1, 0, (size_t)100000 * 4, stream);
  hipMemsetAsync(rowsum2, 0, (size_t)50000 * 4, stream);
  hipMemsetAsync(maskA,   0, (size_t)50000 * 4, stream);
  hipMemsetAsync(out,     0, (size_t)10000000 * 4, stream);

  l2norm_rows<<<12500, 256, 0, stream>>>(ent, x0n, NN, 100);

  // layer-1 projections: srcp/dstp per head into (N,200), head-major cols
  dim3 g1(2, (NN + 63) / 64);
  gemm_f32<<<g1, 256, 0, stream>>>(x0n, NN, 100, 100, a_heads + 0,           300, 1, bufS, 200, 100, 0);
  gemm_f32<<<g1, 256, 0, stream>>>(x0n, NN, 100, 100, a_heads + 30000,       300, 1, bufS, 200, 100, 100);
  gemm_f32<<<g1, 256, 0, stream>>>(x0n, NN, 100, 100, a_heads + 100,         300, 1, bufD, 200, 100, 0);
  gemm_f32<<<g1, 256, 0, stream>>>(x0n, NN, 100, 100, a_heads + 30000 + 100, 300, 1, bufD, 200, 100, 100);
  dim3 g2(2, (NRELS + 63) / 64);
  gemm_f32<<<g2, 256, 0, stream>>>(rel, NRELS, 100, 100, a_heads + 200,         300, 1, relp1, 200, 100, 0);
  gemm_f32<<<g2, 256, 0, stream>>>(rel, NRELS, 100, 100, a_heads + 30000 + 200, 300, 1, relp1, 200, 100, 100);

  dot2h<<<12500, 256, 0, stream>>>(bufS, a2_heads, ssrc1, NN);
  dot2h<<<12500, 256, 0, stream>>>(bufD, a2_heads, sdst1, NN);
  dot2h<<<125,   256, 0, stream>>>(relp1, a2_heads, srel1, NRELS);

  edge1<<<93750, 256, 0, stream>>>(edge_list, edge_type, tin, bufD, relp1, ssrc1, sdst1, srel1,
                                   rowsum1, bufX);

  combine1<<<39063, 256, 0, stream>>>(bufS, rowsum1, bufX);

  // out_relation_1 = rel @ W_gat  -> second output chunk
  dim3 g3(4, (NRELS + 63) / 64);
  gemm_f32<<<g3, 256, 0, stream>>>(rel, NRELS, 100, 100, W_gat, 1, 200, outrel, 200, 200, 0);
  gemm_f32<<<g3, 256, 0, stream>>>(outrel, NRELS, 200, 200, a_out + 400, 600, 1, relp2, 200, 200, 0);

  // layer-2 projections
  dim3 g4(4, (NN + 63) / 64);
  gemm_f32<<<g4, 256, 0, stream>>>(bufX, NN, 200, 200, a_out + 0,   600, 1, bufS, 200, 200, 0);
  gemm_f32<<<g4, 256, 0, stream>>>(bufX, NN, 200, 200, a_out + 200, 600, 1, bufD, 200, 200, 0);

  dot1<<<12500, 256, 0, stream>>>(bufS, a2_out, s2src, NN);
  dot1<<<12500, 256, 0, stream>>>(bufD, a2_out, s2dst, NN);
  dot1<<<125,   256, 0, stream>>>(relp2, a2_out, s2rel, NRELS);

  maskset<<<256, 256, 0, stream>>>(binp, maskA);

  edge2<<<93750, 256, 0, stream>>>(edge_list, edge_type, tin, bufD, relp2, s2src, s2dst, s2rel,
                                   rowsum2, out);

  finalk<<<12500, 256, 0, stream>>>(x0n, W_ent, bufS, rowsum2, maskA, out);
}

// Round 3
// 1138.530 us; speedup vs baseline: 1.4045x; 1.4045x over previous
//
#include <hip/hip_runtime.h>
#include <math.h>

#define NN    50000
#define NEDGE 250000
#define NHOPE 125000
#define ETOT  375000   // NEDGE + NHOPE
#define NRELS 500
#define BATCH 65536

// ---------------- row-wise L2 normalize (one wave per row) ----------------
__global__ __launch_bounds__(256) void l2norm_rows(const float* __restrict__ in,
                                                   float* __restrict__ out, int M, int D) {
  int row  = blockIdx.x * 4 + (threadIdx.x >> 6);
  int lane = threadIdx.x & 63;
  if (row >= M) return;
  const float* r = in + (size_t)row * D;
  float ss = 0.f;
  for (int c = lane; c < D; c += 64) { float v = r[c]; ss += v * v; }
  #pragma unroll
  for (int off = 1; off < 64; off <<= 1) ss += __shfl_xor(ss, off);
  float inv = 1.f / fmaxf(sqrtf(ss), 1e-12f);
  float* o = out + (size_t)row * D;
  for (int c = lane; c < D; c += 64) o[c] = r[c] * inv;
}

// ---------------- f32 GEMM: C[i, col0+j] = sum_k A[i,k] * W[j*wsj + k*wsk]
// 128x64 tile, BK=16, 256 threads, 8x4 microtile.
__global__ __launch_bounds__(256) void gemm2_f32(const float* __restrict__ A, int M, int Kd, int lda,
                                                 const float* __restrict__ W, int wsj, int wsk,
                                                 float* __restrict__ C, int ldc, int Ncols, int col0) {
  __shared__ float As[16][132];
  __shared__ float Bs[16][68];
  int tid = threadIdx.x;
  int tx = tid & 15, ty = tid >> 4;
  int row0 = blockIdx.y * 128;
  int colb = blockIdx.x * 64;
  float acc[8][4];
  #pragma unroll
  for (int i = 0; i < 8; ++i)
    #pragma unroll
    for (int j = 0; j < 4; ++j) acc[i][j] = 0.f;
  for (int kt = 0; kt < Kd; kt += 16) {
    #pragma unroll
    for (int l = 0; l < 8; ++l) {
      int idx = tid + l * 256;
      int m = idx >> 4, k = idx & 15;
      int gm = row0 + m, gk = kt + k;
      As[k][m] = (gm < M && gk < Kd) ? A[(size_t)gm * lda + gk] : 0.f;
    }
    #pragma unroll
    for (int l = 0; l < 4; ++l) {
      int idx = tid + l * 256;
      int j = idx >> 4, k = idx & 15;
      int gj = colb + j, gk = kt + k;
      Bs[k][j] = (gj < Ncols && gk < Kd) ? W[(size_t)gj * wsj + (size_t)gk * wsk] : 0.f;
    }
    __syncthreads();
    #pragma unroll
    for (int k = 0; k < 16; ++k) {
      float4 bv = *(const float4*)&Bs[k][tx * 4];
      float4 a0 = *(const float4*)&As[k][ty * 8];
      float4 a1 = *(const float4*)&As[k][ty * 8 + 4];
      float av[8] = {a0.x, a0.y, a0.z, a0.w, a1.x, a1.y, a1.z, a1.w};
      float bb[4] = {bv.x, bv.y, bv.z, bv.w};
      #pragma unroll
      for (int i = 0; i < 8; ++i)
        #pragma unroll
        for (int j = 0; j < 4; ++j)
          acc[i][j] += av[i] * bb[j];
    }
    __syncthreads();
  }
  int gj0 = colb + tx * 4;
  #pragma unroll
  for (int i = 0; i < 8; ++i) {
    int gm = row0 + ty * 8 + i;
    if (gm >= M) continue;
    float* cp = C + (size_t)gm * ldc + col0;
    if (gj0 + 4 <= Ncols) {
      float4 v = {acc[i][0], acc[i][1], acc[i][2], acc[i][3]};
      *(float4*)(cp + gj0) = v;
    } else {
      #pragma unroll
      for (int j = 0; j < 4; ++j) if (gj0 + j < Ncols) cp[gj0 + j] = acc[i][j];
    }
  }
}

// ---------------- per-row dot with a2 (two heads, 100 each) ----------------
__global__ __launch_bounds__(256) void dot2h(const float* __restrict__ P, const float* __restrict__ a2,
                                             float* __restrict__ outp, int M) {
  int row  = blockIdx.x * 4 + (threadIdx.x >> 6);
  int lane = threadIdx.x & 63;
  if (row >= M) return;
  const float* pr = P + (size_t)row * 200;
  float s0 = 0.f, s1 = 0.f;
  for (int k = lane; k < 100; k += 64) {
    s0 += pr[k] * a2[k];
    s1 += pr[100 + k] * a2[100 + k];
  }
  #pragma unroll
  for (int off = 1; off < 64; off <<= 1) { s0 += __shfl_xor(s0, off); s1 += __shfl_xor(s1, off); }
  if (lane == 0) { outp[row * 2] = s0; outp[row * 2 + 1] = s1; }
}

// ---------------- per-row dot with a2 (single, 200) ----------------
__global__ __launch_bounds__(256) void dot1(const float* __restrict__ P, const float* __restrict__ a2,
                                            float* __restrict__ outp, int M) {
  int row  = blockIdx.x * 4 + (threadIdx.x >> 6);
  int lane = threadIdx.x & 63;
  if (row >= M) return;
  const float* pr = P + (size_t)row * 200;
  float s = 0.f;
  for (int k = lane; k < 200; k += 64) s += pr[k] * a2[k];
  #pragma unroll
  for (int off = 1; off < 64; off <<= 1) s += __shfl_xor(s, off);
  if (lane == 0) outp[row] = s;
}

// ---------------- CSR build ----------------
__global__ __launch_bounds__(256) void histk(const int* __restrict__ el, const int* __restrict__ tin,
                                             int* __restrict__ deg) {
  int i = blockIdx.x * 256 + threadIdx.x;
  if (i >= ETOT) return;
  int e0 = (i < NEDGE) ? el[i] : tin[(size_t)(i - NEDGE) * 4 + 3];
  atomicAdd(&deg[e0], 1);
}

__global__ __launch_bounds__(256) void scanA(const int* __restrict__ deg, int* __restrict__ bsum, int n) {
  __shared__ int s[256];
  int t = threadIdx.x;
  int i = blockIdx.x * 256 + t;
  s[t] = (i < n) ? deg[i] : 0;
  __syncthreads();
  for (int off = 128; off > 0; off >>= 1) {
    if (t < off) s[t] += s[t + off];
    __syncthreads();
  }
  if (t == 0) bsum[blockIdx.x] = s[0];
}

__global__ __launch_bounds__(256) void scanB(int* __restrict__ bsum, int nb) {
  __shared__ int s[256];
  int t = threadIdx.x;
  int v = (t < nb) ? bsum[t] : 0;
  s[t] = v;
  __syncthreads();
  for (int off = 1; off < 256; off <<= 1) {
    int add = (t >= off) ? s[t - off] : 0;
    __syncthreads();
    s[t] += add;
    __syncthreads();
  }
  if (t < nb) bsum[t] = s[t] - v;  // exclusive
}

__global__ __launch_bounds__(256) void scanC(const int* __restrict__ deg, const int* __restrict__ bsum,
                                             int* __restrict__ offs, int* __restrict__ pos, int n, int total) {
  __shared__ int s[256];
  int t = threadIdx.x;
  int i = blockIdx.x * 256 + t;
  int v = (i < n) ? deg[i] : 0;
  s[t] = v;
  __syncthreads();
  for (int off = 1; off < 256; off <<= 1) {
    int add = (t >= off) ? s[t - off] : 0;
    __syncthreads();
    s[t] += add;
    __syncthreads();
  }
  if (i < n) {
    int e = bsum[blockIdx.x] + s[t] - v;
    offs[i] = e;
    pos[i]  = e;
  }
  if (i == 0) offs[n] = total;
}

__global__ __launch_bounds__(256) void scatterk(const int* __restrict__ el, const int* __restrict__ et,
                                                const int* __restrict__ tin,
                                                int* __restrict__ pos, int2* __restrict__ edata) {
  int i = blockIdx.x * 256 + threadIdx.x;
  if (i >= ETOT) return;
  int e0, e1, t1, t2f;
  if (i < NEDGE) {
    e0 = el[i]; e1 = el[NEDGE + i]; t1 = et[i]; t2f = 0;
  } else {
    const int* q = tin + (size_t)(i - NEDGE) * 4;
    e0 = q[3]; e1 = q[0]; t1 = q[1]; t2f = q[2] + 1;
  }
  int slot = atomicAdd(&pos[e0], 1);
  edata[slot] = make_int2(e1 | (t1 << 16), t2f);
}

// ---------------- layer-1 gather (2 heads), fused combine+elu ----------------
__global__ __launch_bounds__(256) void gather1(const int* __restrict__ offs, const int2* __restrict__ edata,
                                               const float* __restrict__ srcp, const float* __restrict__ dstp,
                                               const float* __restrict__ relp,
                                               const float* __restrict__ ssrc, const float* __restrict__ sdst,
                                               const float* __restrict__ srel,
                                               float* __restrict__ xout) {
  int node = blockIdx.x * 4 + (threadIdx.x >> 6);
  int lane = threadIdx.x & 63;
  if (node >= NN) return;
  int s = offs[node], e = offs[node + 1];
  float s00 = ssrc[node * 2], s01 = ssrc[node * 2 + 1];
  int c0 = lane, c1 = lane + 64, c2 = lane + 128, c3 = lane + 192;
  float acc0 = 0.f, acc1 = 0.f, acc2 = 0.f, acc3 = 0.f;
  float rs0 = 0.f, rs1 = 0.f;
  for (int q = s; q < e; ++q) {
    int2 ed = edata[q];
    unsigned w0 = (unsigned)ed.x;
    int e1 = (int)(w0 & 0xFFFFu);
    int t1 = (int)(w0 >> 16);
    int t2f = ed.y;
    float p0 = s00 + sdst[e1 * 2]     + srel[t1 * 2];
    float p1 = s01 + sdst[e1 * 2 + 1] + srel[t1 * 2 + 1];
    const float* rd = dstp + (size_t)e1 * 200;
    const float* r1 = relp + t1 * 200;
    float m0, m1, m2, m3;
    if (t2f) {
      int t2 = t2f - 1;
      p0 += srel[t2 * 2]; p1 += srel[t2 * 2 + 1];
      const float* r2 = relp + t2 * 200;
      m0 = rd[c0] + r1[c0] + r2[c0];
      m1 = rd[c1] + r1[c1] + r2[c1];
      m2 = rd[c2] + r1[c2] + r2[c2];
      m3 = (c3 < 200) ? rd[c3] + r1[c3] + r2[c3] : 0.f;
    } else {
      m0 = rd[c0] + r1[c0];
      m1 = rd[c1] + r1[c1];
      m2 = rd[c2] + r1[c2];
      m3 = (c3 < 200) ? rd[c3] + r1[c3] : 0.f;
    }
    p0 = (p0 > 0.f) ? p0 : 0.2f * p0;
    p1 = (p1 > 0.f) ? p1 : 0.2f * p1;
    float ee0 = __expf(-p0), ee1 = __expf(-p1);
    rs0 += ee0; rs1 += ee1;
    acc0 += ee0 * m0;
    acc1 += ((c1 < 100) ? ee0 : ee1) * m1;
    acc2 += ee1 * m2;
    acc3 += ee1 * m3;
  }
  bool has = (e > s);
  float inv0 = has ? 1.f / rs0 : 0.f;
  float inv1 = has ? 1.f / rs1 : 0.f;
  const float* sp = srcp + (size_t)node * 200;
  float* xo = xout + (size_t)node * 200;
  float v;
  v = has ? sp[c0] + acc0 * inv0 : 0.f;                       xo[c0] = (v > 0.f) ? v : expm1f(v);
  v = has ? sp[c1] + acc1 * ((c1 < 100) ? inv0 : inv1) : 0.f; xo[c1] = (v > 0.f) ? v : expm1f(v);
  v = has ? sp[c2] + acc2 * inv1 : 0.f;                       xo[c2] = (v > 0.f) ? v : expm1f(v);
  if (c3 < 200) {
    v = has ? sp[c3] + acc3 * inv1 : 0.f;
    xo[c3] = (v > 0.f) ? v : expm1f(v);
  }
}

// ---------------- layer-2 gather (1 head), fused combine+elu ----------------
__global__ __launch_bounds__(256) void gather2(const int* __restrict__ offs, const int2* __restrict__ edata,
                                               const float* __restrict__ srcp, const float* __restrict__ dstp,
                                               const float* __restrict__ relp,
                                               const float* __restrict__ ssrc, const float* __restrict__ sdst,
                                               const float* __restrict__ srel,
                                               float* __restrict__ hout) {
  int node = blockIdx.x * 4 + (threadIdx.x >> 6);
  int lane = threadIdx.x & 63;
  if (node >= NN) return;
  int s = offs[node], e = offs[node + 1];
  float s0 = ssrc[node];
  int c0 = lane, c1 = lane + 64, c2 = lane + 128, c3 = lane + 192;
  float acc0 = 0.f, acc1 = 0.f, acc2 = 0.f, acc3 = 0.f;
  float rs = 0.f;
  for (int q = s; q < e; ++q) {
    int2 ed = edata[q];
    unsigned w0 = (unsigned)ed.x;
    int e1 = (int)(w0 & 0xFFFFu);
    int t1 = (int)(w0 >> 16);
    int t2f = ed.y;
    float p = s0 + sdst[e1] + srel[t1];
    const float* rd = dstp + (size_t)e1 * 200;
    const float* r1 = relp + t1 * 200;
    float m0, m1, m2, m3;
    if (t2f) {
      int t2 = t2f - 1;
      p += srel[t2];
      const float* r2 = relp + t2 * 200;
      m0 = rd[c0] + r1[c0] + r2[c0];
      m1 = rd[c1] + r1[c1] + r2[c1];
      m2 = rd[c2] + r1[c2] + r2[c2];
      m3 = (c3 < 200) ? rd[c3] + r1[c3] + r2[c3] : 0.f;
    } else {
      m0 = rd[c0] + r1[c0];
      m1 = rd[c1] + r1[c1];
      m2 = rd[c2] + r1[c2];
      m3 = (c3 < 200) ? rd[c3] + r1[c3] : 0.f;
    }
    p = (p > 0.f) ? p : 0.2f * p;
    float ee = __expf(-p);
    rs += ee;
    acc0 += ee * m0; acc1 += ee * m1; acc2 += ee * m2; acc3 += ee * m3;
  }
  bool has = (e > s);
  float inv = has ? 1.f / rs : 0.f;
  const float* sp = srcp + (size_t)node * 200;
  float* ho = hout + (size_t)node * 200;
  float v;
  v = has ? sp[c0] + acc0 * inv : 0.f; ho[c0] = (v > 0.f) ? v : expm1f(v);
  v = has ? sp[c1] + acc1 * inv : 0.f; ho[c1] = (v > 0.f) ? v : expm1f(v);
  v = has ? sp[c2] + acc2 * inv : 0.f; ho[c2] = (v > 0.f) ? v : expm1f(v);
  if (c3 < 200) {
    v = has ? sp[c3] + acc3 * inv : 0.f;
    ho[c3] = (v > 0.f) ? v : expm1f(v);
  }
}

// ---------------- mask scatter ----------------
__global__ __launch_bounds__(256) void maskset(const int* __restrict__ bi, float* __restrict__ maskA) {
  int t = blockIdx.x * 256 + threadIdx.x;
  if (t < BATCH) maskA[bi[t * 3 + 2]] = 1.0f;
}

// ---------------- final: out = l2norm(xw + mask * h2elu), one wave/row, in place ----------------
__global__ __launch_bounds__(256) void finalk2(const float* __restrict__ xw, const float* __restrict__ h2,
                                               const float* __restrict__ maskA, float* __restrict__ out) {
  int row  = blockIdx.x * 4 + (threadIdx.x >> 6);
  int lane = threadIdx.x & 63;
  if (row >= NN) return;
  float m = maskA[row];
  const float* xr = xw + (size_t)row * 200;
  const float* hr = h2 + (size_t)row * 200;
  int c0 = lane, c1 = lane + 64, c2 = lane + 128, c3 = lane + 192;
  float v0 = xr[c0] + m * hr[c0];
  float v1 = xr[c1] + m * hr[c1];
  float v2 = xr[c2] + m * hr[c2];
  float v3 = (c3 < 200) ? xr[c3] + m * hr[c3] : 0.f;
  float ss = v0 * v0 + v1 * v1 + v2 * v2 + v3 * v3;
  #pragma unroll
  for (int off = 1; off < 64; off <<= 1) ss += __shfl_xor(ss, off);
  float inv = 1.f / fmaxf(sqrtf(ss), 1e-12f);
  float* o = out + (size_t)row * 200;
  o[c0] = v0 * inv; o[c1] = v1 * inv; o[c2] = v2 * inv;
  if (c3 < 200) o[c3] = v3 * inv;
}

extern "C" void kernel_launch(void* const* d_in, const int* in_sizes, int n_in,
                              void* d_out, int out_size, void* d_ws, size_t ws_size,
                              hipStream_t stream) {
  (void)in_sizes; (void)n_in; (void)out_size; (void)ws_size;
  const float* ent      = (const float*)d_in[0];
  const float* rel      = (const float*)d_in[1];
  const float* a_heads  = (const float*)d_in[3];
  const float* a2_heads = (const float*)d_in[4];
  const float* W_gat    = (const float*)d_in[5];
  const float* a_out    = (const float*)d_in[6];
  const float* a2_out   = (const float*)d_in[7];
  const float* W_ent    = (const float*)d_in[8];
  const int* edge_list  = (const int*)d_in[9];
  const int* edge_type  = (const int*)d_in[10];
  const int* tin        = (const int*)d_in[11];
  const int* binp       = (const int*)d_in[12];

  float* out    = (float*)d_out;
  float* outrel = out + 10000000;   // (500,200)
  float* x0n    = out;              // (N,100) lives in d_out until xw GEMM consumes it

  float* ws    = (float*)d_ws;
  float* bufS  = ws;               // N*200 : srcp1 -> srcp2
  float* bufD  = ws + 10000000;    // N*200 : dstp1 -> dstp2
  float* bufX  = ws + 20000000;    // N*200 : x (layer-1 out) -> xw
  float* relp1 = ws + 30000000;    // 500*200
  float* relp2 = ws + 30100000;    // 500*200
  float* ssrc1 = ws + 30200000;    // N*2
  float* sdst1 = ws + 30300000;    // N*2
  float* s2src = ws + 30400000;    // N
  float* s2dst = ws + 30450000;    // N
  float* srel1 = ws + 30500000;    // 500*2
  float* s2rel = ws + 30501000;    // 500
  float* maskA = ws + 30502000;    // N
  int*   ibase = (int*)(ws + 30552000);
  int*   deg   = ibase;            // N
  int*   offs  = ibase + 50000;    // N+1
  int*   pos   = ibase + 100064;   // N
  int*   bsum  = ibase + 150064;   // 256
  int2*  edata = (int2*)(ibase + 150320); // ETOT int2

  hipMemsetAsync(deg,   0, (size_t)NN * 4, stream);
  hipMemsetAsync(maskA, 0, (size_t)NN * 4, stream);

  l2norm_rows<<<12500, 256, 0, stream>>>(ent, x0n, NN, 100);

  // ---- CSR build (shared by both layers) ----
  histk<<<(ETOT + 255) / 256, 256, 0, stream>>>(edge_list, tin, deg);
  scanA<<<196, 256, 0, stream>>>(deg, bsum, NN);
  scanB<<<1, 256, 0, stream>>>(bsum, 196);
  scanC<<<196, 256, 0, stream>>>(deg, bsum, offs, pos, NN, ETOT);
  scatterk<<<(ETOT + 255) / 256, 256, 0, stream>>>(edge_list, edge_type, tin, pos, edata);

  // ---- layer-1 projections ----
  dim3 g1(2, (NN + 127) / 128);
  gemm2_f32<<<g1, 256, 0, stream>>>(x0n, NN, 100, 100, a_heads + 0,           300, 1, bufS, 200, 100, 0);
  gemm2_f32<<<g1, 256, 0, stream>>>(x0n, NN, 100, 100, a_heads + 30000,       300, 1, bufS, 200, 100, 100);
  gemm2_f32<<<g1, 256, 0, stream>>>(x0n, NN, 100, 100, a_heads + 100,         300, 1, bufD, 200, 100, 0);
  gemm2_f32<<<g1, 256, 0, stream>>>(x0n, NN, 100, 100, a_heads + 30000 + 100, 300, 1, bufD, 200, 100, 100);
  dim3 g2(2, (NRELS + 127) / 128);
  gemm2_f32<<<g2, 256, 0, stream>>>(rel, NRELS, 100, 100, a_heads + 200,         300, 1, relp1, 200, 100, 0);
  gemm2_f32<<<g2, 256, 0, stream>>>(rel, NRELS, 100, 100, a_heads + 30000 + 200, 300, 1, relp1, 200, 100, 100);

  dot2h<<<12500, 256, 0, stream>>>(bufS, a2_heads, ssrc1, NN);
  dot2h<<<12500, 256, 0, stream>>>(bufD, a2_heads, sdst1, NN);
  dot2h<<<125,   256, 0, stream>>>(relp1, a2_heads, srel1, NRELS);

  gather1<<<12500, 256, 0, stream>>>(offs, edata, bufS, bufD, relp1, ssrc1, sdst1, srel1, bufX);

  // ---- layer-2 projections (read bufX, overwrite bufS/bufD) ----
  dim3 g4(4, (NN + 127) / 128);
  gemm2_f32<<<g4, 256, 0, stream>>>(bufX, NN, 200, 200, a_out + 0,   600, 1, bufS, 200, 200, 0);
  gemm2_f32<<<g4, 256, 0, stream>>>(bufX, NN, 200, 200, a_out + 200, 600, 1, bufD, 200, 200, 0);

  dim3 g3(4, (NRELS + 127) / 128);
  gemm2_f32<<<g3, 256, 0, stream>>>(rel, NRELS, 100, 100, W_gat, 1, 200, outrel, 200, 200, 0);
  gemm2_f32<<<g3, 256, 0, stream>>>(outrel, NRELS, 200, 200, a_out + 400, 600, 1, relp2, 200, 200, 0);

  // xw = x0n @ W_entities -> bufX (x no longer needed; x0n in d_out consumed here)
  gemm2_f32<<<g4, 256, 0, stream>>>(x0n, NN, 100, 100, W_ent, 1, 200, bufX, 200, 200, 0);

  dot1<<<12500, 256, 0, stream>>>(bufS, a2_out, s2src, NN);
  dot1<<<12500, 256, 0, stream>>>(bufD, a2_out, s2dst, NN);
  dot1<<<125,   256, 0, stream>>>(relp2, a2_out, s2rel, NRELS);

  maskset<<<256, 256, 0, stream>>>(binp, maskA);

  // h2 (elu-applied) written into d_out[0:10M] (x0n already consumed)
  gather2<<<12500, 256, 0, stream>>>(offs, edata, bufS, bufD, relp2, s2src, s2dst, s2rel, out);

  finalk2<<<12500, 256, 0, stream>>>(bufX, out, maskA, out);
}